// Round 7
// baseline (7060.286 us; speedup 1.0000x reference)
//
#include <hip/hip_runtime.h>

#define T_STEPS 2048
#define BATCH   256
#define HID     512
#define NG      16   // gate-slice blocks per batch group (h-cols 512/NG = 32 each)
#define NB      16   // batch groups (rows 256/NB = 16 each)
#define RING    6    // h ring slots (sentinel dataflow protocol)
#define SENT    0x3C3C3C3C  // fp16 pair (1.0586,1.0586) — unreachable: |h|<=1.0 => halves <= 0x3C00

typedef _Float16 half8 __attribute__((ext_vector_type(8)));
typedef float f32x4 __attribute__((ext_vector_type(4)));
typedef int int4v __attribute__((ext_vector_type(4)));

__device__ __forceinline__ float sigmoid_f(float v) {
    return 1.f / (1.f + __expf(-v));
}
__device__ __forceinline__ float tanh_f(float v) {
    float a = fabsf(v);
    float e = __expf(2.f * a);
    float r = 1.f - 2.f / (e + 1.f);
    return copysignf(r, v);
}

// grid = 256 blocks (g = blockIdx&15 batch group, j = blockIdx>>4 gate slice)
// block = 256 threads = 4 waves, K-split (wave w owns k in [128w,128w+128)).
//
// Sentinel-dataflow sync; this round's single change vs R6: the end-of-step
// vmcnt(0) drain is DELETED. Rationale: vmcnt is a single FIFO counter, so the
// next poll's own vmcnt(0) retires this step's reset+h stores anyway — before
// any step-t+1 store is issued. The store-ack leg (~600-1000cy) now overlaps
// the poll's load round trip instead of preceding it serially.
//   Induction (re-verified): stores(t) retired by poll(t+1) vmcnt(0), which
//   precedes stores(t+1) issue. For slot σ: h-store(σ,t) -> polled t+1 ->
//   reset(σ,t+2) -> ack'd by poll(t+3) -> next h-store(σ,t+6); consumers
//   re-read σ at t+7, transitively after the reset is visible. Margin >=3.
//   WAR on rewrite: unchanged chain, margin 5.
// To keep the loop free of compiler-emitted VMEM (whose conservative
// vmcnt(0) before the x-use would re-insert a hidden mid-step drain), the
// x prefetch rides in the poll asm as a 5th load (proven in R4), and x(0)
// is loaded by a pre-loop asm with its own drain.
// Register-lifetime invariant: every poll exit path has vmcnt==0 (loads all
// landed) — no dangling VMEM writers into reusable VGPRs (the R4 bug class).
__global__ __launch_bounds__(256, 1) void lstm_persistent(
    const float* __restrict__ x,     // (T,B)
    const float* __restrict__ Wih,   // (4H,1)
    const float* __restrict__ Whh,   // (4H,H)
    const float* __restrict__ bih,   // (4H)
    const float* __restrict__ bhh,   // (4H)
    const float* __restrict__ Wlin,  // (1,H)
    _Float16* __restrict__ hbuf,     // [RING][B][H] fp16
    float* __restrict__ partial)     // [NG][B]
{
    const int tid  = threadIdx.x;
    const int g    = blockIdx.x & 15;   // batch group
    const int j    = blockIdx.x >> 4;   // gate slice
    const int wave = tid >> 6;          // k-slice owner: k in [128*wave, 128*wave+128)
    const int lane = tid & 63;
    const int quad = lane >> 4;
    const int ln16 = lane & 15;

    // [tb][wave][batch row 16][ (gt*2+ch)*16 + pos , pad to 130 ]
    // write: b64 pairs at pos quad*4 (+2); read: b64 at pos cp&15. 0 conflicts (R6).
    __shared__ float lds_g[2][4][16][130];

    // ---- stationary weights: fp16 MFMA fragments in registers ----
    // bf[gate][colhalf][ksl] holds Whh[gate*512 + j*32 + ch*16 + ln16][k],
    // k = (wave*4 + ksl)*32 + quad*8 + e. A-operand after the operand swap.
    half8 bf[4][2][4];
    #pragma unroll
    for (int gt = 0; gt < 4; ++gt) {
        #pragma unroll
        for (int ch = 0; ch < 2; ++ch) {
            const float* wr = Whh + (size_t)(gt * 512 + j * 32 + ch * 16 + ln16) * HID;
            #pragma unroll
            for (int ksl = 0; ksl < 4; ++ksl) {
                int k0 = (wave * 4 + ksl) * 32 + quad * 8;
                half8 v;
                #pragma unroll
                for (int e = 0; e < 8; ++e) v[e] = (_Float16)wr[k0 + e];
                bf[gt][ch][ksl] = v;
            }
        }
    }

    const int row_e = tid >> 4;          // epilogue row 0..15
    const int cp    = (tid & 15) * 2;    // epilogue col pair 0,2,..,30

    // per-thread epilogue constants (x weights only; bias rides in acc-init)
    float wxA[4], wxB[4];
    #pragma unroll
    for (int gt = 0; gt < 4; ++gt) {
        int r0 = gt * 512 + j * 32 + cp;
        wxA[gt] = Wih[r0];
        wxB[gt] = Wih[r0 + 1];
    }

    // acc-init vectors: wave 0 carries the bias, other waves zero (added once
    // across the 4 wave-partials). MFMA dst != src -> no per-step copies.
    f32x4 biasv[4][2];
    #pragma unroll
    for (int gt = 0; gt < 4; ++gt) {
        #pragma unroll
        for (int ch = 0; ch < 2; ++ch) {
            f32x4 v;
            #pragma unroll
            for (int r = 0; r < 4; ++r) {
                int idx = gt * 512 + j * 32 + ch * 16 + quad * 4 + r;
                v[r] = (wave == 0) ? (bih[idx] + bhh[idx]) : 0.f;
            }
            biasv[gt][ch] = v;
        }
    }

    float c0 = 0.f, c1 = 0.f;            // cell state (fp32, register-resident)
    float hl0 = 0.f, hl1 = 0.f;          // last h values (fp32)
    bool  dead = false;                  // sticky bailout

    // x(0) via asm + drain: keeps ALL in-loop VMEM hand-issued (no compiler
    // waitcnt can appear inside the step loop).
    float x_cur;
    {
        unsigned long long xaddr0 = (unsigned long long)(x + (size_t)g * 16 + row_e);
        asm volatile("global_load_dword %0, %1, off\n\t"
                     "s_waitcnt vmcnt(0)"
                     : "=v"(x_cur) : "v"(xaddr0) : "memory");
    }

    int s_in = 0, s_out = 1, s_rst = 5;

    for (int t = 0; t < T_STEPS; ++t) {
        // ---- poll own fragment lines of slot s_in (the poll IS the load) ----
        // vmcnt(0) here also retires last step's reset+h stores: store-ack
        // overlaps the load flight (this replaces the deleted end drain).
        unsigned long long haddr = (unsigned long long)(
            (const char*)hbuf
            + ((size_t)s_in * (BATCH * HID) + (size_t)(g * 16 + ln16) * HID) * 2
            + wave * 256 + quad * 16);
        unsigned long long xaddr = (unsigned long long)(
            x + (size_t)(t + 1 < T_STEPS ? t + 1 : t) * BATCH + g * 16 + row_e);

        int4v h0, h1, h2, h3;
        float x_next;
        asm volatile(
            "global_load_dwordx4 %0, %5, off sc0 sc1\n\t"
            "global_load_dwordx4 %1, %5, off offset:64 sc0 sc1\n\t"
            "global_load_dwordx4 %2, %5, off offset:128 sc0 sc1\n\t"
            "global_load_dwordx4 %3, %5, off offset:192 sc0 sc1\n\t"
            "global_load_dword %4, %6, off\n\t"
            "s_waitcnt vmcnt(0)"
            : "=&v"(h0), "=&v"(h1), "=&v"(h2), "=&v"(h3), "=&v"(x_next)
            : "v"(haddr), "v"(xaddr) : "memory");
        {
            bool ok = true;
            #pragma unroll
            for (int e = 0; e < 4; ++e) {
                ok = ok && (h0[e] != (int)SENT) && (h1[e] != (int)SENT)
                        && (h2[e] != (int)SENT) && (h3[e] != (int)SENT);
            }
            if (__ballot(ok) != ~0ull && !dead) {
                unsigned it = 0;
                for (;;) {
                    asm volatile(
                        "global_load_dwordx4 %0, %4, off sc0 sc1\n\t"
                        "global_load_dwordx4 %1, %4, off offset:64 sc0 sc1\n\t"
                        "global_load_dwordx4 %2, %4, off offset:128 sc0 sc1\n\t"
                        "global_load_dwordx4 %3, %4, off offset:192 sc0 sc1\n\t"
                        "s_waitcnt vmcnt(0)"
                        : "=&v"(h0), "=&v"(h1), "=&v"(h2), "=&v"(h3)
                        : "v"(haddr) : "memory");
                    ok = true;
                    #pragma unroll
                    for (int e = 0; e < 4; ++e) {
                        ok = ok && (h0[e] != (int)SENT) && (h1[e] != (int)SENT)
                                && (h2[e] != (int)SENT) && (h3[e] != (int)SENT);
                    }
                    if (__ballot(ok) == ~0ull) break;
                    if (++it > 100000000u) { dead = true; break; }
                }
            }
        }

        // ---- 32 MFMAs (swapped operands -> C^T), bias-seeded k-chains ----
        f32x4 acc[4][2];
        #define KSTEP0(hx) {                                                          \
            half8 af = __builtin_bit_cast(half8, hx);                                 \
            _Pragma("unroll")                                                         \
            for (int gt = 0; gt < 4; ++gt) {                                          \
                acc[gt][0] = __builtin_amdgcn_mfma_f32_16x16x32_f16(bf[gt][0][0], af, biasv[gt][0], 0, 0, 0); \
                acc[gt][1] = __builtin_amdgcn_mfma_f32_16x16x32_f16(bf[gt][1][0], af, biasv[gt][1], 0, 0, 0); \
            } }
        #define KSTEP(ksl, hx) {                                                      \
            half8 af = __builtin_bit_cast(half8, hx);                                 \
            _Pragma("unroll")                                                         \
            for (int gt = 0; gt < 4; ++gt) {                                          \
                acc[gt][0] = __builtin_amdgcn_mfma_f32_16x16x32_f16(bf[gt][0][ksl], af, acc[gt][0], 0, 0, 0); \
                acc[gt][1] = __builtin_amdgcn_mfma_f32_16x16x32_f16(bf[gt][1][ksl], af, acc[gt][1], 0, 0, 0); \
            } }
        KSTEP0(h0) KSTEP(1, h1) KSTEP(2, h2) KSTEP(3, h3)
        #undef KSTEP0
        #undef KSTEP

        // C^T layout: col(ln16) = batch row, row(quad*4+r) = gate-col.
        const int tb = t & 1;
        #pragma unroll
        for (int gt = 0; gt < 4; ++gt) {
            #pragma unroll
            for (int ch = 0; ch < 2; ++ch) {
                float* dst = &lds_g[tb][wave][ln16][(gt * 2 + ch) * 16 + quad * 4];
                *(float2*)(dst)     = make_float2(acc[gt][ch][0], acc[gt][ch][1]);
                *(float2*)(dst + 2) = make_float2(acc[gt][ch][2], acc[gt][ch][3]);
            }
        }
        __syncthreads();   // the ONLY barrier per step

        // ---- reset consumed slot s_rst (own 1KB region, 1 dword/thread) ----
        {
            unsigned long long radr = (unsigned long long)(
                (char*)hbuf
                + ((size_t)s_rst * (BATCH * HID)
                   + (size_t)(g * 16 + row_e) * HID + j * 32 + cp) * 2);
            unsigned sv = SENT;
            asm volatile("global_store_dword %0, %1, off sc0 sc1"
                         : : "v"(radr), "v"(sv) : "memory");
        }

        // ---- epilogue: reduce 4 wave-partials, activations, c/h update ----
        const float xin = x_cur;
        const int chR = cp >> 4, pR = cp & 15;
        float sA[4] = {0.f, 0.f, 0.f, 0.f};
        float sB[4] = {0.f, 0.f, 0.f, 0.f};
        #pragma unroll
        for (int w = 0; w < 4; ++w) {
            #pragma unroll
            for (int gt = 0; gt < 4; ++gt) {
                float2 v = *(const float2*)&lds_g[tb][w][row_e][(gt * 2 + chR) * 16 + pR];
                sA[gt] += v.x;
                sB[gt] += v.y;
            }
        }
        float hv0, hv1;
        {
            float gi = sA[0] + xin * wxA[0];
            float gf = sA[1] + xin * wxA[1];
            float gg = sA[2] + xin * wxA[2];
            float go = sA[3] + xin * wxA[3];
            float iv = sigmoid_f(gi), fv = sigmoid_f(gf), gv = tanh_f(gg), ov = sigmoid_f(go);
            c0 = fv * c0 + iv * gv;
            hv0 = ov * tanh_f(c0);
        }
        {
            float gi = sB[0] + xin * wxB[0];
            float gf = sB[1] + xin * wxB[1];
            float gg = sB[2] + xin * wxB[2];
            float go = sB[3] + xin * wxB[3];
            float iv = sigmoid_f(gi), fv = sigmoid_f(gf), gv = tanh_f(gg), ov = sigmoid_f(go);
            c1 = fv * c1 + iv * gv;
            hv1 = ov * tanh_f(c1);
        }
        hl0 = hv0; hl1 = hv1;

        // ---- store h(t+1) into slot s_out; data store IS the publish ----
        // NO end drain: next poll's vmcnt(0) retires this (+ the reset) before
        // any step-t+1 store is issued. Stores write no registers, so the
        // in-flight tail at loop exit is harmless (kernel end completes them).
        {
            _Float16 p0 = (_Float16)hv0, p1 = (_Float16)hv1;
            unsigned hbits = ((unsigned)__builtin_bit_cast(unsigned short, p1) << 16)
                           |  (unsigned)__builtin_bit_cast(unsigned short, p0);
            unsigned long long sadr = (unsigned long long)(
                (char*)hbuf
                + ((size_t)s_out * (BATCH * HID)
                   + (size_t)(g * 16 + row_e) * HID + j * 32 + cp) * 2);
            asm volatile("global_store_dword %0, %1, off sc0 sc1"
                         : : "v"(sadr), "v"(hbits) : "memory");
        }

        x_cur = x_next;
        s_rst = s_in;
        s_in  = s_out;
        s_out = (s_out + 1 == RING) ? 0 : s_out + 1;
    }

    // ---- partial output: sum over this block's 32 h-cols per row ----
    float p = hl0 * Wlin[j * 32 + cp] + hl1 * Wlin[j * 32 + cp + 1];
    #pragma unroll
    for (int off = 8; off; off >>= 1) p += __shfl_down(p, off, 16);
    if ((tid & 15) == 0) partial[(size_t)j * BATCH + g * 16 + row_e] = p;
}

__global__ void lstm_finalize(const float* __restrict__ partial,
                              const float* __restrict__ blin,
                              float* __restrict__ out)
{
    int b = threadIdx.x;
    float s = blin[0];
    #pragma unroll
    for (int jj = 0; jj < NG; ++jj) s += partial[(size_t)jj * BATCH + b];
    out[b] = s;
}

extern "C" void kernel_launch(void* const* d_in, const int* in_sizes, int n_in,
                              void* d_out, int out_size, void* d_ws, size_t ws_size,
                              hipStream_t stream) {
    const float* x    = (const float*)d_in[0];
    const float* Wih  = (const float*)d_in[1];
    const float* Whh  = (const float*)d_in[2];
    const float* bih  = (const float*)d_in[3];
    const float* bhh  = (const float*)d_in[4];
    const float* Wlin = (const float*)d_in[5];
    const float* blin = (const float*)d_in[6];

    char* ws = (char*)d_ws;
    _Float16* hbuf    = (_Float16*)ws;                   // RING * 256KB = 1.5 MB
    float*    partial = (float*)(ws + (2 << 20));        // 16 KB

    const size_t slot_bytes = (size_t)BATCH * HID * sizeof(_Float16);  // 256 KB
    // slot 0 = zeros (h(-1)); slots 1..5 = sentinel (0x3C bytes -> 0x3C3C3C3C dwords)
    hipMemsetAsync(hbuf, 0, slot_bytes, stream);
    hipMemsetAsync((char*)hbuf + slot_bytes, 0x3C, (RING - 1) * slot_bytes, stream);

    lstm_persistent<<<dim3(256), dim3(256), 0, stream>>>(
        x, Wih, Whh, bih, bhh, Wlin, hbuf, partial);
    lstm_finalize<<<dim3(1), dim3(256), 0, stream>>>(partial, blin, (float*)d_out);
}

// Round 9
// 4552.215 us; speedup vs baseline: 1.5510x; 1.5510x over previous
//
#include <hip/hip_runtime.h>

#define T_STEPS 2048
#define BATCH   256
#define HID     512
#define NG      16   // gate-slice blocks per batch group (h-cols 512/NG = 32 each)
#define NB      16   // batch groups (rows 256/NB = 16 each)
#define RING    6    // h ring slots (sentinel dataflow protocol)
#define SENT    0x3C3C3C3C  // fp16 pair (1.0586,1.0586) — unreachable: |h|<=1.0 => halves <= 0x3C00

typedef _Float16 half8 __attribute__((ext_vector_type(8)));
typedef float f32x4 __attribute__((ext_vector_type(4)));
typedef int int4v __attribute__((ext_vector_type(4)));

__device__ __forceinline__ float sigmoid_f(float v) {
    return 1.f / (1.f + __expf(-v));
}
__device__ __forceinline__ float tanh_f(float v) {
    float a = fabsf(v);
    float e = __expf(2.f * a);
    float r = 1.f - 2.f / (e + 1.f);
    return copysignf(r, v);
}

// grid = 256 blocks (g = blockIdx&15 batch group, j = blockIdx>>4 gate slice)
// block = 256 threads = 4 waves, K-split (wave w owns k in [128w,128w+128)).
//
// Sentinel-dataflow sync (no flags, no publish barrier, no flag->data trip):
//  - h lives in a 6-slot ring; slot for step t input = t%6.
//  - Producers store h via sc0|sc1 (MALL-coherent); consumers poll their own
//    A-fragment lines until all dwords != SENT — the poll IS the data load.
//  - Consumed slot (t-1)%6 is reset to SENT after the mid-step barrier (the
//    barrier proves, via this block's 4 waves having collectively observed all
//    16 peer outputs of step t-1, that every peer wave finished reading it).
//  - End-of-step s_waitcnt vmcnt(0) makes resets/stores visible before this
//    block's NEXT store is issued -> inductively visible before any peer's
//    re-poll of that slot 5 steps later. WAR on slot rewrite follows from the
//    same dataflow chain (poll success at t => peers passed barrier t-1 =>
//    their reads of older slots retired).
//  - SESSION NOTE (R1-R7): this exact schedule is the measured optimum.
//    The end drain doubles as the poll's self-alignment delay (R7: removing
//    it costs +54% via premature-sample retry quantization). Scope lowering
//    (R1/R2), intra-block streaming (R3), 2-deep sampling (R5), and C-shrink
//    (R6) all regressed or were neutral. The kernel sits at the serial
//    cross-block latency floor: 2048 exchanges x ~2.2us.
__global__ __launch_bounds__(256, 1) void lstm_persistent(
    const float* __restrict__ x,     // (T,B)
    const float* __restrict__ Wih,   // (4H,1)
    const float* __restrict__ Whh,   // (4H,H)
    const float* __restrict__ bih,   // (4H)
    const float* __restrict__ bhh,   // (4H)
    const float* __restrict__ Wlin,  // (1,H)
    _Float16* __restrict__ hbuf,     // [RING][B][H] fp16
    float* __restrict__ partial)     // [NG][B]
{
    const int tid  = threadIdx.x;
    const int g    = blockIdx.x & 15;   // batch group
    const int j    = blockIdx.x >> 4;   // gate slice
    const int wave = tid >> 6;          // k-slice owner: k in [128*wave, 128*wave+128)
    const int lane = tid & 63;
    const int quad = lane >> 4;
    const int ln16 = lane & 15;

    // pad 34 (even): bank = (2*row + col) % 32 -> <=2-way on writes (free),
    // b64 reads ~4-way worst. Double-buffered (t&1): lets us run ONE barrier/step.
    __shared__ float lds_part[2][4][4][16][34];

    // ---- stationary weights: fp16 MFMA B-fragments in registers ----
    // bf[gate][colhalf][ksl]: B[k][n] = Whh[gate*512 + j*32 + colhalf*16 + ln16][k],
    // k = (wave*4 + ksl)*32 + quad*8 + e
    half8 bf[4][2][4];
    #pragma unroll
    for (int gt = 0; gt < 4; ++gt) {
        #pragma unroll
        for (int ch = 0; ch < 2; ++ch) {
            const float* wr = Whh + (size_t)(gt * 512 + j * 32 + ch * 16 + ln16) * HID;
            #pragma unroll
            for (int ksl = 0; ksl < 4; ++ksl) {
                int k0 = (wave * 4 + ksl) * 32 + quad * 8;
                half8 v;
                #pragma unroll
                for (int e = 0; e < 8; ++e) v[e] = (_Float16)wr[k0 + e];
                bf[gt][ch][ksl] = v;
            }
        }
    }

    const int row_e = tid >> 4;          // epilogue row 0..15
    const int cp    = (tid & 15) * 2;    // epilogue col pair 0,2,..,30

    // per-thread epilogue constants in registers (was LDS)
    float wxA[4], wxB[4], bsA[4], bsB[4];
    #pragma unroll
    for (int gt = 0; gt < 4; ++gt) {
        int r0 = gt * 512 + j * 32 + cp;
        wxA[gt] = Wih[r0];
        wxB[gt] = Wih[r0 + 1];
        bsA[gt] = bih[r0] + bhh[r0];
        bsB[gt] = bih[r0 + 1] + bhh[r0 + 1];
    }

    float c0 = 0.f, c1 = 0.f;            // cell state (fp32, register-resident)
    float hl0 = 0.f, hl1 = 0.f;          // last h values (fp32)
    bool  dead = false;                  // sticky bailout

    float x_cur = x[(size_t)g * 16 + row_e];   // x for t=0

    int s_in = 0, s_out = 1, s_rst = 5;

    for (int t = 0; t < T_STEPS; ++t) {
        // ---- poll own A-fragment lines of slot s_in (the poll IS the load) ----
        unsigned long long haddr = (unsigned long long)(
            (const char*)hbuf
            + ((size_t)s_in * (BATCH * HID) + (size_t)(g * 16 + ln16) * HID) * 2
            + wave * 256 + quad * 16);
        int4v h0, h1, h2, h3;
        {
            unsigned it = 0;
            for (;;) {
                asm volatile(
                    "global_load_dwordx4 %0, %4, off sc0 sc1\n\t"
                    "global_load_dwordx4 %1, %4, off offset:64 sc0 sc1\n\t"
                    "global_load_dwordx4 %2, %4, off offset:128 sc0 sc1\n\t"
                    "global_load_dwordx4 %3, %4, off offset:192 sc0 sc1\n\t"
                    "s_waitcnt vmcnt(0)"
                    : "=&v"(h0), "=&v"(h1), "=&v"(h2), "=&v"(h3)
                    : "v"(haddr) : "memory");
                bool ok = true;
                #pragma unroll
                for (int e = 0; e < 4; ++e) {
                    ok = ok && (h0[e] != (int)SENT) && (h1[e] != (int)SENT)
                            && (h2[e] != (int)SENT) && (h3[e] != (int)SENT);
                }
                if (__ballot(ok) == ~0ull || dead) break;
                if (++it > 100000000u) { dead = true; break; }
            }
        }

        // prefetch x for next step (overlaps MFMA + epilogue)
        float x_next = x[(size_t)(t + 1 < T_STEPS ? t + 1 : t) * BATCH + g * 16 + row_e];

        // ---- 32 MFMAs: 4 gates x 2 col-halves x 4 k-sub-slices (partial sums) ----
        f32x4 acc[4][2];
        #pragma unroll
        for (int gt = 0; gt < 4; ++gt) {
            acc[gt][0] = (f32x4){0.f, 0.f, 0.f, 0.f};
            acc[gt][1] = (f32x4){0.f, 0.f, 0.f, 0.f};
        }
        #define KSTEP(ksl, hx) {                                                      \
            half8 af = __builtin_bit_cast(half8, hx);                                 \
            _Pragma("unroll")                                                         \
            for (int gt = 0; gt < 4; ++gt) {                                          \
                acc[gt][0] = __builtin_amdgcn_mfma_f32_16x16x32_f16(af, bf[gt][0][ksl], acc[gt][0], 0, 0, 0); \
                acc[gt][1] = __builtin_amdgcn_mfma_f32_16x16x32_f16(af, bf[gt][1][ksl], acc[gt][1], 0, 0, 0); \
            } }
        KSTEP(0, h0) KSTEP(1, h1) KSTEP(2, h2) KSTEP(3, h3)
        #undef KSTEP

        // C layout: col = ln16, row = quad*4 + r  -> per-wave partials to LDS
        const int tb = t & 1;
        #pragma unroll
        for (int gt = 0; gt < 4; ++gt) {
            #pragma unroll
            for (int r = 0; r < 4; ++r) {
                lds_part[tb][wave][gt][quad * 4 + r][ln16]      = acc[gt][0][r];
                lds_part[tb][wave][gt][quad * 4 + r][16 + ln16] = acc[gt][1][r];
            }
        }
        __syncthreads();   // the ONLY barrier per step

        // ---- reset consumed slot s_rst (own 1KB region, 1 dword/thread) ----
        {
            unsigned long long radr = (unsigned long long)(
                (char*)hbuf
                + ((size_t)s_rst * (BATCH * HID)
                   + (size_t)(g * 16 + row_e) * HID + j * 32 + cp) * 2);
            unsigned sv = SENT;
            asm volatile("global_store_dword %0, %1, off sc0 sc1"
                         : : "v"(radr), "v"(sv) : "memory");
        }

        // ---- epilogue: reduce 4 wave-partials, activations, c/h update ----
        const float xin = x_cur;
        float sA[4] = {0.f, 0.f, 0.f, 0.f};
        float sB[4] = {0.f, 0.f, 0.f, 0.f};
        #pragma unroll
        for (int w = 0; w < 4; ++w) {
            #pragma unroll
            for (int gt = 0; gt < 4; ++gt) {
                float2 v = *(const float2*)&lds_part[tb][w][gt][row_e][cp];
                sA[gt] += v.x;
                sB[gt] += v.y;
            }
        }
        float hv0, hv1;
        {
            float gi = sA[0] + xin * wxA[0] + bsA[0];
            float gf = sA[1] + xin * wxA[1] + bsA[1];
            float gg = sA[2] + xin * wxA[2] + bsA[2];
            float go = sA[3] + xin * wxA[3] + bsA[3];
            float iv = sigmoid_f(gi), fv = sigmoid_f(gf), gv = tanh_f(gg), ov = sigmoid_f(go);
            c0 = fv * c0 + iv * gv;
            hv0 = ov * tanh_f(c0);
        }
        {
            float gi = sB[0] + xin * wxB[0] + bsB[0];
            float gf = sB[1] + xin * wxB[1] + bsB[1];
            float gg = sB[2] + xin * wxB[2] + bsB[2];
            float go = sB[3] + xin * wxB[3] + bsB[3];
            float iv = sigmoid_f(gi), fv = sigmoid_f(gf), gv = tanh_f(gg), ov = sigmoid_f(go);
            c1 = fv * c1 + iv * gv;
            hv1 = ov * tanh_f(c1);
        }
        hl0 = hv0; hl1 = hv1;

        // ---- store h(t+1) into slot s_out; data store IS the publish ----
        {
            _Float16 p0 = (_Float16)hv0, p1 = (_Float16)hv1;
            unsigned hbits = ((unsigned)__builtin_bit_cast(unsigned short, p1) << 16)
                           |  (unsigned)__builtin_bit_cast(unsigned short, p0);
            unsigned long long sadr = (unsigned long long)(
                (char*)hbuf
                + ((size_t)s_out * (BATCH * HID)
                   + (size_t)(g * 16 + row_e) * HID + j * 32 + cp) * 2);
            asm volatile("global_store_dword %0, %1, off sc0 sc1"
                         : : "v"(sadr), "v"(hbits) : "memory");
        }
        // end-of-step drain: resets + h store acked before this block's NEXT
        // store is issued (visibility induction); doubles as the poll's
        // self-alignment delay (R7: removing it costs +54%).
        asm volatile("s_waitcnt vmcnt(0)" ::: "memory");

        x_cur = x_next;
        s_rst = s_in;
        s_in  = s_out;
        s_out = (s_out + 1 == RING) ? 0 : s_out + 1;
    }

    // ---- partial output: sum over this block's 32 h-cols per row ----
    float p = hl0 * Wlin[j * 32 + cp] + hl1 * Wlin[j * 32 + cp + 1];
    #pragma unroll
    for (int off = 8; off; off >>= 1) p += __shfl_down(p, off, 16);
    if ((tid & 15) == 0) partial[(size_t)j * BATCH + g * 16 + row_e] = p;
}

__global__ void lstm_finalize(const float* __restrict__ partial,
                              const float* __restrict__ blin,
                              float* __restrict__ out)
{
    int b = threadIdx.x;
    float s = blin[0];
    #pragma unroll
    for (int jj = 0; jj < NG; ++jj) s += partial[(size_t)jj * BATCH + b];
    out[b] = s;
}

extern "C" void kernel_launch(void* const* d_in, const int* in_sizes, int n_in,
                              void* d_out, int out_size, void* d_ws, size_t ws_size,
                              hipStream_t stream) {
    const float* x    = (const float*)d_in[0];
    const float* Wih  = (const float*)d_in[1];
    const float* Whh  = (const float*)d_in[2];
    const float* bih  = (const float*)d_in[3];
    const float* bhh  = (const float*)d_in[4];
    const float* Wlin = (const float*)d_in[5];
    const float* blin = (const float*)d_in[6];

    char* ws = (char*)d_ws;
    _Float16* hbuf    = (_Float16*)ws;                   // RING * 256KB = 1.5 MB
    float*    partial = (float*)(ws + (2 << 20));        // 16 KB

    const size_t slot_bytes = (size_t)BATCH * HID * sizeof(_Float16);  // 256 KB
    // slot 0 = zeros (h(-1)); slots 1..5 = sentinel (0x3C bytes -> 0x3C3C3C3C dwords)
    hipMemsetAsync(hbuf, 0, slot_bytes, stream);
    hipMemsetAsync((char*)hbuf + slot_bytes, 0x3C, (RING - 1) * slot_bytes, stream);

    lstm_persistent<<<dim3(256), dim3(256), 0, stream>>>(
        x, Wih, Whh, bih, bhh, Wlin, hbuf, partial);
    lstm_finalize<<<dim3(1), dim3(256), 0, stream>>>(partial, blin, (float*)d_out);
}